// Round 6
// baseline (393.854 us; speedup 1.0000x reference)
//
#include <hip/hip_runtime.h>

// ---------- types ----------
typedef unsigned short bf16_t;                                    // raw bf16 bits
typedef __bf16 bf16x8 __attribute__((ext_vector_type(8)));        // MFMA A/B frag (4 VGPRs)
typedef float  v4f   __attribute__((ext_vector_type(4)));         // MFMA C/D frag

// round-to-nearest-even f32 -> bf16 (branchless; inputs are finite)
__device__ __forceinline__ bf16_t f2bf(float f) {
    union { float f; unsigned u; } a; a.f = f;
    unsigned r = a.u + 0x7FFFu + ((a.u >> 16) & 1u);
    return (bf16_t)(r >> 16);
}
__device__ __forceinline__ unsigned fbits(float f) {
    union { float f; unsigned u; } a; a.f = f; return a.u;
}
// RTNE pack two f32 -> bf16x2 dword
__device__ __forceinline__ unsigned pk2(float lo, float hi) {
    return (unsigned)f2bf(lo) | ((unsigned)f2bf(hi) << 16);
}
// truncating pack (P only: bias cancels between numerator and denominator l)
__device__ __forceinline__ unsigned pk2t(float lo, float hi) {
    return (fbits(lo) >> 16) | (fbits(hi) & 0xFFFF0000u);
}

// async global->LDS, 16B per lane; LDS dest = wave-uniform base + lane*16
#define GL16(g, l) __builtin_amdgcn_global_load_lds( \
    (__attribute__((address_space(1))) void*)(g),    \
    (__attribute__((address_space(3))) void*)(l), 16, 0, 0)

// Q is pre-scaled by log2(e)/sqrt(64) so attention uses raw v_exp_f32 (2^x)
#define QSCALE 0.18033688011f

// ---------- fused fp32 -> bf16 convert: x + Wq + Wk + Wv + Wo in one launch ----------
__global__ __launch_bounds__(256) void cvt_all(
    const float4* __restrict__ x,  const float4* __restrict__ wq,
    const float4* __restrict__ wk, const float4* __restrict__ wv,
    const float4* __restrict__ wo,
    ushort4* __restrict__ xb, ushort4* __restrict__ wqkv, ushort4* __restrict__ wob) {
    int i = blockIdx.x * 256 + threadIdx.x;          // 0 .. 3145728-1 (float4 units)
    const float4* s; ushort4* d; int off;
    if (i < 2097152) { s = x; d = xb; off = i; }
    else {
        int wdx = (i - 2097152) >> 18;               // 262144 float4 per weight
        off = (i - 2097152) & 262143;
        if      (wdx == 0) { s = wq; d = wqkv; }
        else if (wdx == 1) { s = wk; d = wqkv + 262144; }
        else if (wdx == 2) { s = wv; d = wqkv + 524288; }
        else               { s = wo; d = wob; }
    }
    float4 v = s[off];
    ushort4 o;
    o.x = f2bf(v.x); o.y = f2bf(v.y); o.z = f2bf(v.z); o.w = f2bf(v.w);
    d[off] = o;
}

// ---------- GEMM mainloop: acc[i][j] = D[a-row][b-row], A-operand rows from PA_,
// B-operand rows from PB_ (both row-major [rows][1024] bf16). 128x128 tile, BK=32.
// Staging uses source-side xor swizzle (key=(row>>1)&3 on 16B chunks) so the
// LDS b128 fragment reads are 2-way-bank (free); reads apply the matching xor.
#define GEMM_MAINLOOP(PA_, baseA_, PB_, baseB_)                                        \
    __shared__ bf16_t SMEM[8192];                                                      \
    bf16_t* As = SMEM; bf16_t* Bs = SMEM + 4096;                                       \
    const int tid = threadIdx.x;                                                       \
    const int w = tid >> 6, lane = tid & 63;                                           \
    const int lrow = lane & 15, lq = lane >> 4;                                        \
    const int srow = w * 16 + (lane >> 2);                                             \
    const int sk = ((lane & 3) ^ ((lane >> 3) & 3)) * 8;                               \
    const int rswz = (lq ^ ((lrow >> 1) & 3)) * 8;                                     \
    const int wm = (w & 1) * 64, wn = (w >> 1) * 64;                                   \
    v4f acc[4][4];                                                                     \
    _Pragma("unroll") for (int i = 0; i < 4; ++i)                                      \
        _Pragma("unroll") for (int j = 0; j < 4; ++j)                                  \
            acc[i][j] = (v4f){0.f, 0.f, 0.f, 0.f};                                     \
    for (int k0 = 0; k0 < 1024; k0 += 32) {                                            \
        __syncthreads();                                                               \
        GL16(PA_ + (size_t)(baseA_ + srow) * 1024 + k0 + sk,      (char*)As + w * 1024);    \
        GL16(PA_ + (size_t)(baseA_ + 64 + srow) * 1024 + k0 + sk, (char*)As + 4096 + w * 1024); \
        GL16(PB_ + (size_t)(baseB_ + srow) * 1024 + k0 + sk,      (char*)Bs + w * 1024);    \
        GL16(PB_ + (size_t)(baseB_ + 64 + srow) * 1024 + k0 + sk, (char*)Bs + 4096 + w * 1024); \
        __syncthreads();                                                               \
        bf16x8 af[4], bf[4];                                                           \
        _Pragma("unroll") for (int i = 0; i < 4; ++i)                                  \
            af[i] = *(const bf16x8*)&As[(wm + i * 16 + lrow) * 32 + rswz];             \
        _Pragma("unroll") for (int j = 0; j < 4; ++j)                                  \
            bf[j] = *(const bf16x8*)&Bs[(wn + j * 16 + lrow) * 32 + rswz];             \
        _Pragma("unroll") for (int i = 0; i < 4; ++i)                                  \
            _Pragma("unroll") for (int j = 0; j < 4; ++j)                              \
                acc[i][j] = __builtin_amdgcn_mfma_f32_16x16x32_bf16(af[i], bf[j],      \
                                                                    acc[i][j], 0, 0, 0); \
    }

// QKV projection. For Q/K blocks A-operand = W rows (lane gets 4 consecutive d ->
// packed b64 stores into (b,h,t,d)). For V blocks A-operand = x rows (4 consecutive
// t -> packed b64 stores into V^T (b,h,d,t)). No LDS epilogue needed anywhere.
__global__ __launch_bounds__(256) void gemm_qkv_kernel(
    const bf16_t* __restrict__ xb, const bf16_t* __restrict__ Wqkv,
    bf16_t* __restrict__ Qb, bf16_t* __restrict__ Kb, bf16_t* __restrict__ Vtb) {
    const int x = blockIdx.x;                 // 0..23 (n-block), n = x*128
    const int m0 = blockIdx.y * 128;          // token rows
    const bool isV = (x >= 16);
    const bf16_t* PA = isV ? xb : Wqkv;
    const bf16_t* PB = isV ? Wqkv : xb;
    const int baseA = isV ? m0 : x * 128;
    const int baseB = isV ? x * 128 : m0;
    GEMM_MAINLOOP(PA, baseA, PB, baseB)
    if (!isV) {
        bf16_t* dst = (x < 8) ? Qb : Kb;
        const float sc = (x < 8) ? QSCALE : 1.0f;
        const int nb = (x < 8) ? x * 128 : x * 128 - 1024;
#pragma unroll
        for (int i = 0; i < 4; ++i)
#pragma unroll
            for (int j = 0; j < 4; ++j) {
                int n = nb + wm + i * 16 + lq * 4;       // d-chunk base (4 consec)
                int t = m0 + wn + j * 16 + lrow;
                int bb = t >> 12, tt = t & 4095;
                int hh = n >> 6, dd = n & 63;
                uint2 u;
                u.x = pk2(acc[i][j][0] * sc, acc[i][j][1] * sc);
                u.y = pk2(acc[i][j][2] * sc, acc[i][j][3] * sc);
                *(uint2*)&dst[(((size_t)bb * 16 + hh) * 4096 + tt) * 64 + dd] = u;
            }
    } else {
#pragma unroll
        for (int i = 0; i < 4; ++i)
#pragma unroll
            for (int j = 0; j < 4; ++j) {
                int t = m0 + wm + i * 16 + lq * 4;       // t-chunk base (4 consec)
                int vr = x * 128 - 2048 + wn + j * 16 + lrow;  // V^T row (0..1023)
                int bb = t >> 12, tt = t & 4095;
                uint2 u;
                u.x = pk2(acc[i][j][0], acc[i][j][1]);
                u.y = pk2(acc[i][j][2], acc[i][j][3]);
                *(uint2*)&Vtb[((size_t)bb * 1024 + vr) * 4096 + tt] = u;
            }
    }
}

// Output projection: out = Ob @ Wo^T + bo (fp32). A-operand = Wo rows -> lane holds
// 4 consecutive n -> float4 stores.
__global__ __launch_bounds__(256) void gemm_out_kernel(
    const bf16_t* __restrict__ Ob, const bf16_t* __restrict__ Wob,
    const float* __restrict__ bo, float* __restrict__ out) {
    const int x = blockIdx.x;                 // 0..7
    const int m0 = blockIdx.y * 128;
    const int nA = x * 128;
    GEMM_MAINLOOP(Wob, nA, Ob, m0)
#pragma unroll
    for (int i = 0; i < 4; ++i) {
        int n = nA + wm + i * 16 + lq * 4;
        float4 bv = *(const float4*)&bo[n];
#pragma unroll
        for (int j = 0; j < 4; ++j) {
            int m = m0 + wn + j * 16 + lrow;
            float4 o = {acc[i][j][0] + bv.x, acc[i][j][1] + bv.y,
                        acc[i][j][2] + bv.z, acc[i][j][3] + bv.w};
            *(float4*)&out[(size_t)m * 1024 + n] = o;
        }
    }
}

// ---------- causal flash attention, v6 ----------
// v4/v5 block-cooperative structure (128 q-rows/block, 64-col k-tiles staged via
// global_load_lds, double-buffered), but: UNPAIRED tasks with LPT dispatch order
// (j = 31 - blockIdx.x; longest first), grid 1024 blocks -> 3 blocks/CU (48 KB LDS,
// 144 KB/CU) = 12 waves/CU for latency hiding. Corrected staging swizzle key
// ((row>>1)&3) makes K/V b128 LDS reads 2-way-bank (free). PV uses swapped MFMA
// operands so O-epilogue is packed b64 stores with one rcp per 16 rows.
__global__ __launch_bounds__(256, 2) void attn_kernel(
    const bf16_t* __restrict__ Q, const bf16_t* __restrict__ K,
    const bf16_t* __restrict__ Vt, bf16_t* __restrict__ O) {
    __shared__ bf16_t Kls[2][2][64 * 32];   // [buf][d-half][trow*32]   16 KB
    __shared__ bf16_t Vls[2][2][64 * 32];   // [buf][t-half][drow*32]   16 KB
    __shared__ bf16_t Plds[4][32 * 64];     // per-wave P (swizzled)    16 KB
    const int tid = threadIdx.x;
    const int w = tid >> 6, lane = tid & 63;
    const int lrow = lane & 15, lq = lane >> 4;
    const int bh = blockIdx.y;
    const int j = 31 - blockIdx.x;          // LPT: longest tasks dispatched first
    const int q0 = j * 128;
    const int q0w = q0 + w * 32;            // this wave's 32 rows
    const int nt = 2 * j + 2;
    const int wlast = 2 * j + (w >> 1);     // wave's diagonal tile

    const bf16_t* Qh = Q + (size_t)bh * (4096 * 64);
    const bf16_t* Kh = K + (size_t)bh * (4096 * 64);
    const bf16_t* Vh = Vt + (size_t)bh * (64 * 4096);
    bf16_t* Pw = Plds[w];
    const int b = bh >> 4, h = bh & 15;

    // staging lane mapping: 16B per lane; global source chunk xor (row>>1)&3
    const int srow = lane >> 2;                           // 0..15
    const int soff = ((lane & 3) ^ ((srow >> 1) & 3)) * 8;
    const int kswz = (lq ^ ((lrow >> 1) & 3)) * 8;        // matching read xor
    const int pswz = (lrow & 7) << 1;                     // P 8B-granule xor

    bf16x8 ones;
#pragma unroll
    for (int i = 0; i < 8; ++i) ones[i] = (__bf16)1.0f;

    bf16x8 qf[2][2];                        // Q B-operand frags (pre-scaled)
#pragma unroll
    for (int sub = 0; sub < 2; ++sub)
#pragma unroll
        for (int dk = 0; dk < 2; ++dk)
            qf[sub][dk] = *(const bf16x8*)&Qh[(size_t)(q0w + sub * 16 + lrow) * 64 + dk * 32 + lq * 8];

    v4f oacc[2][4];
    v4f lacc[2];
#pragma unroll
    for (int s2 = 0; s2 < 2; ++s2) {
        lacc[s2] = (v4f){0.f, 0.f, 0.f, 0.f};
#pragma unroll
        for (int d = 0; d < 4; ++d) oacc[s2][d] = (v4f){0.f, 0.f, 0.f, 0.f};
    }

    // stage tile kt into buf: 16 GL16 (8 K + 8 V), 4 per wave
    auto stage = [&](int kt, int buf) {
        const size_t kc0 = (size_t)kt << 6;
#pragma unroll
        for (int i = 0; i < 2; ++i) {
            int u = w * 2 + i;                 // 0..7
            int half = u >> 2, rg = u & 3;
            GL16(Kh + (kc0 + rg * 16 + srow) * 64 + half * 32 + soff,
                 (char*)&Kls[buf][half][rg * 512]);
            GL16(Vh + (size_t)(rg * 16 + srow) * 4096 + kc0 + half * 32 + soff,
                 (char*)&Vls[buf][half][rg * 512]);
        }
    };

    stage(0, 0);
    for (int kt = 0; kt < nt; ++kt) {
        const int buf = kt & 1;
        __syncthreads();                 // drains this wave's GL16s + all waves
        if (kt + 1 < nt) stage(kt + 1, buf ^ 1);
        if (kt > wlast) continue;        // fully-masked tile: loads+barriers only
        const int kc0 = kt << 6;
        const bool diag = (kt == wlast);

        // K fragments (A-operand) and V fragments from LDS, swizzle-matched
        bf16x8 kf0[4], kf1[4];
#pragma unroll
        for (int c = 0; c < 4; ++c) {
            kf0[c] = *(const bf16x8*)&Kls[buf][0][(c * 16 + lrow) * 32 + kswz];
            kf1[c] = *(const bf16x8*)&Kls[buf][1][(c * 16 + lrow) * 32 + kswz];
        }
        bf16x8 vf[4][2];
#pragma unroll
        for (int d = 0; d < 4; ++d)
#pragma unroll
            for (int kh = 0; kh < 2; ++kh)
                vf[d][kh] = *(const bf16x8*)&Vls[buf][kh][(d * 16 + lrow) * 32 + kswz];

#pragma unroll
        for (int sub = 0; sub < 2; ++sub) {
            const int qrow = sub * 16 + lrow;       // local q (lane's S^T col)
            const int qglob = q0w + qrow;

            // S^T = K Q^T : lane holds q=lrow-dim, t = kc0 + c*16 + lq*4 + r
            v4f st[4];
#pragma unroll
            for (int c = 0; c < 4; ++c) {
                v4f t0v = (v4f){0.f, 0.f, 0.f, 0.f};
                t0v = __builtin_amdgcn_mfma_f32_16x16x32_bf16(kf0[c], qf[sub][0], t0v, 0, 0, 0);
                st[c] = __builtin_amdgcn_mfma_f32_16x16x32_bf16(kf1[c], qf[sub][1], t0v, 0, 0, 0);
            }

            // P = 2^S (mask to 0 after exp on diag tile); contiguous b64 stores
#pragma unroll
            for (int c = 0; c < 4; ++c) {
                float p[4];
#pragma unroll
                for (int r = 0; r < 4; ++r) {
                    float pv = __builtin_amdgcn_exp2f(st[c][r]);
                    if (diag) {
                        int tg = kc0 + c * 16 + lq * 4 + r;
                        pv = (tg > qglob) ? 0.f : pv;
                    }
                    p[r] = pv;
                }
                uint2 u;
                u.x = pk2t(p[0], p[1]);
                u.y = pk2t(p[2], p[3]);
                *(uint2*)&Pw[qrow * 64 + (((c * 4 + lq) ^ pswz) << 2)] = u;
            }

            // P fragments (xor-matched b128 reads); usable as A or B operand
            bf16x8 pf[2];
#pragma unroll
            for (int kh = 0; kh < 2; ++kh) {
                int s0 = kh * 8 + lq * 2;
                pf[kh] = *(const bf16x8*)&Pw[qrow * 64 + ((s0 ^ pswz) << 2)];
            }

            // Swapped operands: l = ones^T P (all rows identical -> per-q in lrow),
            // O^T = V P^T (lane gets 4 consecutive d for fixed t=lrow)
#pragma unroll
            for (int kh = 0; kh < 2; ++kh) {
                lacc[sub] = __builtin_amdgcn_mfma_f32_16x16x32_bf16(ones, pf[kh], lacc[sub], 0, 0, 0);
#pragma unroll
                for (int d = 0; d < 4; ++d)
                    oacc[sub][d] = __builtin_amdgcn_mfma_f32_16x16x32_bf16(vf[d][kh], pf[kh], oacc[sub][d], 0, 0, 0);
            }
        }
    }

    // epilogue: O = oacc / l ; packed b64 stores, t = q0w+sub*16+lrow, d chunk = d4*16+lq*4
#pragma unroll
    for (int sub = 0; sub < 2; ++sub) {
        float rl = 1.0f / lacc[sub][0];     // all 4 lanesregs identical by construction
        size_t rowbase = ((size_t)b * 4096 + q0w + sub * 16 + lrow) * 1024 + h * 64 + lq * 4;
#pragma unroll
        for (int d = 0; d < 4; ++d) {
            uint2 u;
            u.x = pk2(oacc[sub][d][0] * rl, oacc[sub][d][1] * rl);
            u.y = pk2(oacc[sub][d][2] * rl, oacc[sub][d][3] * rl);
            *(uint2*)&O[rowbase + d * 16] = u;
        }
    }
}

// ---------- launch ----------
extern "C" void kernel_launch(void* const* d_in, const int* in_sizes, int n_in,
                              void* d_out, int out_size, void* d_ws, size_t ws_size,
                              hipStream_t stream) {
    const float* x  = (const float*)d_in[0];
    const float* Wq = (const float*)d_in[1];
    const float* Wk = (const float*)d_in[2];
    const float* Wv = (const float*)d_in[3];
    const float* Wo = (const float*)d_in[4];
    const float* bo = (const float*)d_in[5];
    float* out = (float*)d_out;

    char* ws = (char*)d_ws;
    bf16_t* xb   = (bf16_t*)(ws + 0);           // 8192x1024      16.78 MB
    bf16_t* Wqkv = (bf16_t*)(ws + 16777216);    // 3072x1024       6.29 MB
    bf16_t* Wob  = (bf16_t*)(ws + 23068672);    // 1024x1024       2.10 MB
    bf16_t* Qb   = (bf16_t*)(ws + 25165824);    // (b,h,t,d)      16.78 MB
    bf16_t* Kb   = (bf16_t*)(ws + 41943040);    // (b,h,t,d)      16.78 MB
    bf16_t* Vtb  = (bf16_t*)(ws + 58720256);    // (b,h,d,t)      16.78 MB
    bf16_t* Ob   = (bf16_t*)(ws + 75497472);    // 8192x1024      16.78 MB

    // fused converts (x, Wq, Wk, Wv, Wo) in one launch
    cvt_all<<<12288, 256, 0, stream>>>((const float4*)x, (const float4*)Wq,
                                       (const float4*)Wk, (const float4*)Wv,
                                       (const float4*)Wo,
                                       (ushort4*)xb, (ushort4*)Wqkv, (ushort4*)Wob);

    // QKV projection (M=8192, N=3072), packed epilogues
    gemm_qkv_kernel<<<dim3(24, 64), 256, 0, stream>>>(xb, Wqkv, Qb, Kb, Vtb);

    // causal flash attention (unpaired LPT tasks, 3 blocks/CU)
    attn_kernel<<<dim3(32, 32), 256, 0, stream>>>(Qb, Kb, Vtb, Ob);

    // output projection (M=8192, N=1024) + bias, float4 epilogue
    gemm_out_kernel<<<dim3(8, 64), 256, 0, stream>>>(Ob, Wob, bo, out);
}